// Round 1
// baseline (372.922 us; speedup 1.0000x reference)
//
#include <hip/hip_runtime.h>
#include <math.h>

#define BN 4096   // batch
#define DN 16384  // features per row

// Host-side python computes these in double, then JAX demotes to f32 at use.
static constexpr double kWFirstD = 2.0 - 10.0 * (2.0 / 49.0);          // 78/49
static constexpr double kWLastD  = 2.0 - kWFirstD;                      // 20/49
static constexpr double kStepD   = (kWFirstD - kWLastD) / (BN - 1);

// ---------------------------------------------------------------------------
// Kernel 1: per-row squared-sum -> difficulty[row] = 0.5*loss + 0.5*||g||2
// One block per row, 256 threads, float4 loads (16 B/lane, fully coalesced).
// Memory-bound: 256 MiB streamed once.
// ---------------------------------------------------------------------------
__global__ __launch_bounds__(256)
void sspl_rownorm(const float* __restrict__ loss,
                  const float* __restrict__ grads,
                  float* __restrict__ diff_out) {
    const int row = blockIdx.x;
    const float4* __restrict__ g =
        reinterpret_cast<const float4*>(grads + (size_t)row * DN);
    float s = 0.0f;
#pragma unroll
    for (int it = 0; it < DN / 4 / 256; ++it) {   // 16 iterations
        const float4 v = g[it * 256 + threadIdx.x];
        s += v.x * v.x + v.y * v.y + v.z * v.z + v.w * v.w;
    }
#pragma unroll
    for (int off = 32; off > 0; off >>= 1) s += __shfl_down(s, off, 64);
    __shared__ float wave_part[4];
    const int lane = threadIdx.x & 63;
    const int wave = threadIdx.x >> 6;
    if (lane == 0) wave_part[wave] = s;
    __syncthreads();
    if (threadIdx.x == 0) {
        const float tot = wave_part[0] + wave_part[1] + wave_part[2] + wave_part[3];
        diff_out[row] = 0.5f * loss[row] + 0.5f * sqrtf(tot);
    }
}

// ---------------------------------------------------------------------------
// Kernel 2: stable-sort rank of each difficulty + weighted contribution.
// rank(j) = #{d_i < d_j} + #{d_i == d_j && i < j}   (== stable argsort pos).
// 256 blocks x 256 threads: block b handles j in [16b, 16b+16); 16 threads
// cooperate per j, each scanning 256 of the 4096 LDS-resident difficulties.
// i = t*16 + seg -> 16 distinct LDS banks per iteration (conflict-free).
// ---------------------------------------------------------------------------
__global__ __launch_bounds__(256)
void sspl_rank(const float* __restrict__ loss,
               const float* __restrict__ diff,
               float* __restrict__ contrib) {
    __shared__ float sd[BN];  // 16 KiB
    for (int i = threadIdx.x; i < BN; i += 256) sd[i] = diff[i];
    __syncthreads();

    const int jj  = threadIdx.x >> 4;   // local j (0..15)
    const int seg = threadIdx.x & 15;   // segment of the i-scan (0..15)
    const int j   = (blockIdx.x << 4) + jj;
    const float dj = sd[j];

    int cnt = 0;
#pragma unroll 8
    for (int t = 0; t < 256; ++t) {
        const int i = (t << 4) | seg;
        const float di = sd[i];
        cnt += (di < dj || (di == dj && i < j)) ? 1 : 0;
    }
    // reduce across the 16 cooperating lanes (contiguous within one wave)
#pragma unroll
    for (int off = 8; off > 0; off >>= 1) cnt += __shfl_down(cnt, off, 16);

    if (seg == 0) {
        const float w = (float)kWFirstD - (float)kStepD * (float)cnt;
        contrib[j] = loss[j] * w;
    }
}

// ---------------------------------------------------------------------------
// Kernel 3: deterministic mean of the 4096 contributions -> d_out[0].
// ---------------------------------------------------------------------------
__global__ __launch_bounds__(256)
void sspl_mean(const float* __restrict__ contrib, float* __restrict__ out0) {
    float s = 0.0f;
#pragma unroll
    for (int it = 0; it < BN / 256; ++it) s += contrib[it * 256 + threadIdx.x];
#pragma unroll
    for (int off = 32; off > 0; off >>= 1) s += __shfl_down(s, off, 64);
    __shared__ float wave_part[4];
    const int lane = threadIdx.x & 63;
    const int wave = threadIdx.x >> 6;
    if (lane == 0) wave_part[wave] = s;
    __syncthreads();
    if (threadIdx.x == 0) {
        out0[0] = (wave_part[0] + wave_part[1] + wave_part[2] + wave_part[3]) *
                  (1.0f / BN);
    }
}

extern "C" void kernel_launch(void* const* d_in, const int* in_sizes, int n_in,
                              void* d_out, int out_size, void* d_ws, size_t ws_size,
                              hipStream_t stream) {
    const float* loss  = (const float*)d_in[0];   // [4096]
    const float* grads = (const float*)d_in[1];   // [4096 x 16384]
    float* out = (float*)d_out;                   // [0]=weighted_loss, [1..4096]=difficulty
    float* contrib = (float*)d_ws;                // 4096 floats of scratch

    sspl_rownorm<<<BN, 256, 0, stream>>>(loss, grads, out + 1);
    sspl_rank<<<BN / 16, 256, 0, stream>>>(loss, out + 1, contrib);
    sspl_mean<<<1, 256, 0, stream>>>(contrib, out);
}